// Round 19
// baseline (165.561 us; speedup 1.0000x reference)
//
#include <hip/hip_runtime.h>
#include <hip/hip_bf16.h>
#include <stdint.h>

#define NWIN 216      // 6^3 windows
#define NVOX 110592   // 48^3

typedef __bf16 bf16_t;
typedef __attribute__((ext_vector_type(8))) __bf16 bf16x8;
typedef __attribute__((ext_vector_type(4))) float f32x4;
typedef __attribute__((ext_vector_type(16))) float f32x16;
typedef __attribute__((ext_vector_type(4))) unsigned int u32x4;
typedef __attribute__((ext_vector_type(2))) unsigned int u32x2;

__device__ __forceinline__ f32x4 mfma16(bf16x8 a, bf16x8 b, f32x4 c) {
  return __builtin_amdgcn_mfma_f32_16x16x32_bf16(a, b, c, 0, 0, 0);
}
__device__ __forceinline__ f32x16 mfma32(bf16x8 a, bf16x8 b, f32x16 c) {
  return __builtin_amdgcn_mfma_f32_32x32x16_bf16(a, b, c, 0, 0, 0);
}

__device__ __forceinline__ float fexp2(float x) {
  return __builtin_amdgcn_exp2f(x);
}

__device__ __forceinline__ unsigned int pk2(float lo, float hi) {
  unsigned short l = __builtin_bit_cast(unsigned short, (bf16_t)lo);
  unsigned short h = __builtin_bit_cast(unsigned short, (bf16_t)hi);
  return (unsigned int)l | ((unsigned int)h << 16);
}

// Exchange a.hi(lanes32-63) <-> b.lo(lanes0-31).
__device__ __forceinline__ void swap_half(unsigned int& a, unsigned int& b) {
#if __has_builtin(__builtin_amdgcn_permlane32_swap)
  u32x2 r = __builtin_amdgcn_permlane32_swap(a, b, false, false);
  a = r[0]; b = r[1];
#else
  asm("v_permlane32_swap_b32 %0, %1" : "+v"(a), "+v"(b));
#endif
}

// C/D-layout (row = (r&3)+8*(r>>2)+4hi, col = l31) -> A/B-frag layout along the
// row dim: f0 holds rows chunk 0..15 as elems 8hi+e, f1 rows 16..31. This is
// the SAME verified butterfly used for the P->PV fragment (R4+), reused for
// Q/K/V fragment construction (no exp).
__device__ __forceinline__ void pack_fr(const f32x16& S, bf16x8& f0, bf16x8& f1) {
  unsigned int p01 = pk2(S[0], S[1]),   p23 = pk2(S[2], S[3]);
  unsigned int p45 = pk2(S[4], S[5]),   p67 = pk2(S[6], S[7]);
  unsigned int p89 = pk2(S[8], S[9]),   pab = pk2(S[10], S[11]);
  unsigned int pcd = pk2(S[12], S[13]), pef = pk2(S[14], S[15]);
  swap_half(p01, p45);
  swap_half(p23, p67);
  swap_half(p89, pcd);
  swap_half(pab, pef);
  u32x4 u0 = {p01, p23, p45, p67};
  u32x4 u1 = {p89, pab, pcd, pef};
  f0 = __builtin_bit_cast(bf16x8, u0);
  f1 = __builtin_bit_cast(bf16x8, u1);
}

// ---------------- Kernel 1: FUSED qkv + windowed attention ----------------
// One (window, head, half) per 512-thread block, grid 1728. The 85 MB qkv
// intermediate (written by the old qkv kernel, re-read by attn: ~170 MB HBM
// round-trip = ~27us) is eliminated: each block stages its x window as bf16
// in LDS, computes Q (register) and K/V (LDS, in MFMA-fragment form) via
// W x X MFMAs, then runs the R16 attention loop.
//   Q: D = W_q.X   -> D col = q-row = l31 -> pack_fr -> B-frag (qf)
//   K: D = W_k.X   -> D col = k-row = l31 -> pack_fr -> A-frag (kf)
//   V: D = X^T.W_v^T -> D col = d = l31   -> pack_fr -> B-frag (vf)
// kfl/vfl store per-lane u32x4 -> contiguous, conflict-free b128 read/write.
// LDS 136 KB -> 1 block/CU (R9/R10: this kernel is occupancy-insensitive).
// No-max softmax (|s| small); row-sums on MFMA pipe (P x ones).
// att layout: [216 w][512 n][128 hc].

__device__ __forceinline__ void attn_step(bf16x8 kf0, bf16x8 kf1, bf16x8 vf0, bf16x8 vf1,
                                          bf16x8 q0, bf16x8 q1, const f32x16& z, bf16x8 ones,
                                          f32x16& O, f32x16& Sm) {
  f32x16 S = mfma32(kf0, q0, z);
  S = mfma32(kf1, q1, S);
  #pragma unroll
  for (int r = 0; r < 16; ++r) S[r] = fexp2(S[r]);
  bf16x8 pf0, pf1;
  pack_fr(S, pf0, pf1);
  O = mfma32(pf0, vf0, O);
  O = mfma32(pf1, vf1, O);
  Sm = mfma32(pf0, ones, Sm);
  Sm = mfma32(pf1, ones, Sm);
}

__global__ __launch_bounds__(512, 1) void fattn_kernel(const float* __restrict__ x,
                                                       const float* __restrict__ w_qkv,
                                                       bf16_t* __restrict__ att) {
  __shared__ bf16_t xs[512][72];       // [n][c] bf16, 144-B rows   73.7 KB
  __shared__ u32x4 kfl[16][2][64];     // K frags [tile][chunk][lane] 32 KB
  __shared__ u32x4 vfl[16][2][64];     // V frags                     32 KB
  const int blk = blockIdx.x;
  const int wh = blk >> 1, half = blk & 1;
  const int w = wh >> 2, h = wh & 3;
  const int wx = w / 36, wy = (w / 6) % 6, wz = w % 6;
  const int t = threadIdx.x, lane = t & 63, wv = t >> 6;
  const int l31 = lane & 31, hi = lane >> 5;
  const float SC = 0.25505003946337226f;  // log2(e)/sqrt(32)

  // stage x window -> xs[n][c]: c-pair packed b32 writes (from old qkv kernel)
  #pragma unroll
  for (int i = 0; i < 4; ++i) {
    int seg = t + 512 * i;               // 2048 segs: cpair(32) x xy(64)
    int cpair = seg & 31, xy = seg >> 5;
    int ix = xy >> 3, iy = xy & 7;
    const float* s0 = x + (((2 * cpair) * 48 + wx * 8 + ix) * 48 + wy * 8 + iy) * 48 + wz * 8;
    const float* s1 = s0 + 48 * 48 * 48;
    float4 a0 = reinterpret_cast<const float4*>(s0)[0];
    float4 a1 = reinterpret_cast<const float4*>(s0)[1];
    float4 b0 = reinterpret_cast<const float4*>(s1)[0];
    float4 b1 = reinterpret_cast<const float4*>(s1)[1];
    float av[8] = {a0.x, a0.y, a0.z, a0.w, a1.x, a1.y, a1.z, a1.w};
    float bv[8] = {b0.x, b0.y, b0.z, b0.w, b1.x, b1.y, b1.z, b1.w};
    #pragma unroll
    for (int z8 = 0; z8 < 8; ++z8)
      *(unsigned int*)&xs[xy * 8 + z8][2 * cpair] = pk2(av[z8], bv[z8]);
  }

  // W fragments (per lane, direct from global; L2-hot 96 KB):
  // wqf: A-frag of W_q row (h*32+l31), c = cch*16+8hi+e, scaled by SC
  // wkf: A-frag of W_k row (128+h*32+l31)
  // wvf: B-frag of W_v^T col d=l31 == W_v row (256+h*32+l31)
  bf16x8 wqf[4], wkf[4], wvf[4];
  #pragma unroll
  for (int cch = 0; cch < 4; ++cch) {
    const float* q_r = w_qkv + (h * 32 + l31) * 64 + cch * 16 + 8 * hi;
    const float* k_r = q_r + 128 * 64;
    const float* v_r = q_r + 256 * 64;
    float4 u0, u1;
    bf16x8 f;
    u0 = reinterpret_cast<const float4*>(q_r)[0]; u1 = reinterpret_cast<const float4*>(q_r)[1];
    f[0]=(bf16_t)(u0.x*SC); f[1]=(bf16_t)(u0.y*SC); f[2]=(bf16_t)(u0.z*SC); f[3]=(bf16_t)(u0.w*SC);
    f[4]=(bf16_t)(u1.x*SC); f[5]=(bf16_t)(u1.y*SC); f[6]=(bf16_t)(u1.z*SC); f[7]=(bf16_t)(u1.w*SC);
    wqf[cch] = f;
    u0 = reinterpret_cast<const float4*>(k_r)[0]; u1 = reinterpret_cast<const float4*>(k_r)[1];
    f[0]=(bf16_t)u0.x; f[1]=(bf16_t)u0.y; f[2]=(bf16_t)u0.z; f[3]=(bf16_t)u0.w;
    f[4]=(bf16_t)u1.x; f[5]=(bf16_t)u1.y; f[6]=(bf16_t)u1.z; f[7]=(bf16_t)u1.w;
    wkf[cch] = f;
    u0 = reinterpret_cast<const float4*>(v_r)[0]; u1 = reinterpret_cast<const float4*>(v_r)[1];
    f[0]=(bf16_t)u0.x; f[1]=(bf16_t)u0.y; f[2]=(bf16_t)u0.z; f[3]=(bf16_t)u0.w;
    f[4]=(bf16_t)u1.x; f[5]=(bf16_t)u1.y; f[6]=(bf16_t)u1.z; f[7]=(bf16_t)u1.w;
    wvf[cch] = f;
  }
  __syncthreads();

  const f32x16 z = {};
  const int qbase = half * 256 + wv * 32;   // this wave's 32 q-rows

  // Q phase: D = W_q.X over 4 c-chunks; B = X[c][n] col n = qbase+l31
  f32x16 Dq = z;
  #pragma unroll
  for (int cch = 0; cch < 4; ++cch) {
    bf16x8 xb = *(const bf16x8*)&xs[qbase + l31][cch * 16 + 8 * hi];
    Dq = mfma32(wqf[cch], xb, Dq);
  }
  bf16x8 qf0, qf1;
  pack_fr(Dq, qf0, qf1);

  // K,V phase: wave computes tiles 2wv, 2wv+1 (32 k-rows each)
  #pragma unroll
  for (int i = 0; i < 2; ++i) {
    int kt = 2 * wv + i;
    bf16x8 xf[4];
    #pragma unroll
    for (int cch = 0; cch < 4; ++cch)
      xf[cch] = *(const bf16x8*)&xs[kt * 32 + l31][cch * 16 + 8 * hi];
    f32x16 Dk = z, Dv = z;
    #pragma unroll
    for (int cch = 0; cch < 4; ++cch) {
      Dk = mfma32(wkf[cch], xf[cch], Dk);   // D[d][k-col]
      Dv = mfma32(xf[cch], wvf[cch], Dv);   // D[k-row][d-col]
    }
    bf16x8 a, b;
    pack_fr(Dk, a, b);
    kfl[kt][0][lane] = __builtin_bit_cast(u32x4, a);
    kfl[kt][1][lane] = __builtin_bit_cast(u32x4, b);
    pack_fr(Dv, a, b);
    vfl[kt][0][lane] = __builtin_bit_cast(u32x4, a);
    vfl[kt][1][lane] = __builtin_bit_cast(u32x4, b);
  }
  __syncthreads();

  f32x16 O = {}, Sm = {};
  bf16x8 ones;
  #pragma unroll
  for (int e = 0; e < 8; ++e) ones[e] = (bf16_t)1.0f;

  for (int kt = 0; kt < 16; ++kt) {
    bf16x8 kf0 = __builtin_bit_cast(bf16x8, kfl[kt][0][lane]);
    bf16x8 kf1 = __builtin_bit_cast(bf16x8, kfl[kt][1][lane]);
    bf16x8 vf0 = __builtin_bit_cast(bf16x8, vfl[kt][0][lane]);
    bf16x8 vf1 = __builtin_bit_cast(bf16x8, vfl[kt][1][lane]);
    attn_step(kf0, kf1, vf0, vf1, qf0, qf1, z, ones, O, Sm);
  }

  // normalize + store: O/Sm reg r -> row q = (r&3)+8*(r>>2)+4*hi, col d = l31
  #pragma unroll
  for (int r = 0; r < 16; ++r) {
    int qr = (r & 3) + 8 * (r >> 2) + 4 * hi;
    int n = qbase + qr;
    float ri = __builtin_amdgcn_rcpf(Sm[r]);
    att[((size_t)w * 512 + n) * 128 + h * 32 + l31] = (bf16_t)(O[r] * ri);
  }
}

// ---------------- Kernel 2: merge-heads 1x1x1 conv via MFMA ----------------
// Grid 864 = 216 windows x 4 quarters, 256 threads; w_out staged once per
// block into LDS bf16 (R16 proven config).
__global__ __launch_bounds__(256) void proj_kernel(const bf16_t* __restrict__ att,
                                                   const float* __restrict__ w_out,
                                                   const float* __restrict__ b_out,
                                                   float* __restrict__ out) {
  __shared__ bf16_t ws[64][136];   // [o][c] pad 136 -> 17.4 KB
  const int blk = blockIdx.x;
  const int w = blk >> 2, quarter = blk & 3;
  const int wx = w / 36, wy = (w / 6) % 6, wz = w % 6;
  const int t = threadIdx.x, lane = t & 63, wv = t >> 6;
  const int q16 = lane & 15, g = lane >> 4;

  {
    int o = t >> 2, c0 = (t & 3) * 32;
    const float* wr = w_out + o * 128 + c0;
    #pragma unroll
    for (int u = 0; u < 4; ++u) {
      float4 a = reinterpret_cast<const float4*>(wr)[2 * u];
      float4 b = reinterpret_cast<const float4*>(wr)[2 * u + 1];
      *(unsigned int*)&ws[o][c0 + 8 * u]     = pk2(a.x, a.y);
      *(unsigned int*)&ws[o][c0 + 8 * u + 2] = pk2(a.z, a.w);
      *(unsigned int*)&ws[o][c0 + 8 * u + 4] = pk2(b.x, b.y);
      *(unsigned int*)&ws[o][c0 + 8 * u + 6] = pk2(b.z, b.w);
    }
  }
  float4 bias[4];
  #pragma unroll
  for (int ot = 0; ot < 4; ++ot)
    bias[ot] = *reinterpret_cast<const float4*>(b_out + ot * 16 + 4 * g);
  __syncthreads();

  bf16x8 aw[4][4];
  #pragma unroll
  for (int ot = 0; ot < 4; ++ot)
    #pragma unroll
    for (int kc = 0; kc < 4; ++kc)
      aw[ot][kc] = *(const bf16x8*)&ws[ot * 16 + q16][kc * 32 + 8 * g];

  #pragma unroll
  for (int i = 0; i < 2; ++i) {
    int n = quarter * 128 + (wv * 2 + i) * 16 + q16;
    const bf16_t* ar = att + ((size_t)w * 512 + n) * 128;
    bf16x8 bf[4];
    #pragma unroll
    for (int kc = 0; kc < 4; ++kc)
      bf[kc] = *(const bf16x8*)(ar + kc * 32 + 8 * g);
    int ix = n >> 6, iy = (n >> 3) & 7, iz = n & 7;
    int v = ((wx * 8 + ix) * 48 + wy * 8 + iy) * 48 + wz * 8 + iz;
    #pragma unroll
    for (int ot = 0; ot < 4; ++ot) {
      f32x4 acc = {0.f, 0.f, 0.f, 0.f};
      #pragma unroll
      for (int kc = 0; kc < 4; ++kc)
        acc = mfma16(aw[ot][kc], bf[kc], acc);
      #pragma unroll
      for (int r = 0; r < 4; ++r) {
        int o = ot * 16 + 4 * g + r;
        out[(size_t)o * NVOX + v] = acc[r] + ((const float*)&bias[ot])[r];
      }
    }
  }
}

extern "C" void kernel_launch(void* const* d_in, const int* in_sizes, int n_in,
                              void* d_out, int out_size, void* d_ws, size_t ws_size,
                              hipStream_t stream) {
  const float* x     = (const float*)d_in[0];
  const float* w_qkv = (const float*)d_in[1];
  const float* w_out = (const float*)d_in[2];
  const float* b_out = (const float*)d_in[3];
  float* out = (float*)d_out;
  // ws: att bf16 [216][512][128] = 28,311,552 B (qkv intermediate eliminated)
  bf16_t* att = (bf16_t*)d_ws;
  fattn_kernel<<<dim3(NWIN * 4 * 2), dim3(512), 0, stream>>>(x, w_qkv, att);
  proj_kernel<<<dim3(NWIN * 4), dim3(256), 0, stream>>>(att, w_out, b_out, out);
}

// Round 20
// 119.003 us; speedup vs baseline: 1.3912x; 1.3912x over previous
//
#include <hip/hip_runtime.h>
#include <hip/hip_bf16.h>
#include <stdint.h>

#define NWIN 216      // 6^3 windows
#define NVOX 110592   // 48^3

typedef __bf16 bf16_t;
typedef __attribute__((ext_vector_type(8))) __bf16 bf16x8;
typedef __attribute__((ext_vector_type(4))) float f32x4;
typedef __attribute__((ext_vector_type(16))) float f32x16;
typedef __attribute__((ext_vector_type(4))) unsigned int u32x4;
typedef __attribute__((ext_vector_type(2))) unsigned int u32x2;

__device__ __forceinline__ f32x4 mfma16(bf16x8 a, bf16x8 b, f32x4 c) {
  return __builtin_amdgcn_mfma_f32_16x16x32_bf16(a, b, c, 0, 0, 0);
}
__device__ __forceinline__ f32x16 mfma32(bf16x8 a, bf16x8 b, f32x16 c) {
  return __builtin_amdgcn_mfma_f32_32x32x16_bf16(a, b, c, 0, 0, 0);
}

__device__ __forceinline__ float fexp2(float x) {
  return __builtin_amdgcn_exp2f(x);
}

__device__ __forceinline__ unsigned int pk2(float lo, float hi) {
  unsigned short l = __builtin_bit_cast(unsigned short, (bf16_t)lo);
  unsigned short h = __builtin_bit_cast(unsigned short, (bf16_t)hi);
  return (unsigned int)l | ((unsigned int)h << 16);
}

// Exchange a.hi(lanes32-63) <-> b.lo(lanes0-31).
__device__ __forceinline__ void swap_half(unsigned int& a, unsigned int& b) {
#if __has_builtin(__builtin_amdgcn_permlane32_swap)
  u32x2 r = __builtin_amdgcn_permlane32_swap(a, b, false, false);
  a = r[0]; b = r[1];
#else
  asm("v_permlane32_swap_b32 %0, %1" : "+v"(a), "+v"(b));
#endif
}

// C/D-layout (row = (r&3)+8*(r>>2)+4hi, col = l31) -> A/B-frag layout along
// the row dim (verified R19: absmax passed with all three W.X mappings).
__device__ __forceinline__ void pack_fr(const f32x16& S, bf16x8& f0, bf16x8& f1) {
  unsigned int p01 = pk2(S[0], S[1]),   p23 = pk2(S[2], S[3]);
  unsigned int p45 = pk2(S[4], S[5]),   p67 = pk2(S[6], S[7]);
  unsigned int p89 = pk2(S[8], S[9]),   pab = pk2(S[10], S[11]);
  unsigned int pcd = pk2(S[12], S[13]), pef = pk2(S[14], S[15]);
  swap_half(p01, p45);
  swap_half(p23, p67);
  swap_half(p89, pcd);
  swap_half(pab, pef);
  u32x4 u0 = {p01, p23, p45, p67};
  u32x4 u1 = {p89, pab, pcd, pef};
  f0 = __builtin_bit_cast(bf16x8, u0);
  f1 = __builtin_bit_cast(bf16x8, u1);
}

// ---------------- Kernel 0: x transpose/downcast to window layout ----------
// xw[w][n][64] bf16 (14.2 MB). One block per window; same gather as the old
// qkv staging loop, but written to global once instead of re-staged into LDS
// by 8 fused blocks (R19's failure: 8x duplicated staging + 139 KB LDS).
__global__ __launch_bounds__(512, 2) void xprep_kernel(const float* __restrict__ x,
                                                       bf16_t* __restrict__ xw) {
  const int w = blockIdx.x;
  const int wx = w / 36, wy = (w / 6) % 6, wz = w % 6;
  const int t = threadIdx.x;
  #pragma unroll
  for (int i = 0; i < 4; ++i) {
    int seg = t + 512 * i;               // 2048 segs: cpair(32) x xy(64)
    int cpair = seg & 31, xy = seg >> 5;
    int ix = xy >> 3, iy = xy & 7;
    const float* s0 = x + (((2 * cpair) * 48 + wx * 8 + ix) * 48 + wy * 8 + iy) * 48 + wz * 8;
    const float* s1 = s0 + 48 * 48 * 48;
    float4 a0 = reinterpret_cast<const float4*>(s0)[0];
    float4 a1 = reinterpret_cast<const float4*>(s0)[1];
    float4 b0 = reinterpret_cast<const float4*>(s1)[0];
    float4 b1 = reinterpret_cast<const float4*>(s1)[1];
    float av[8] = {a0.x, a0.y, a0.z, a0.w, a1.x, a1.y, a1.z, a1.w};
    float bv[8] = {b0.x, b0.y, b0.z, b0.w, b1.x, b1.y, b1.z, b1.w};
    #pragma unroll
    for (int z8 = 0; z8 < 8; ++z8)
      *(unsigned int*)(xw + ((size_t)w * 512 + xy * 8 + z8) * 64 + 2 * cpair) = pk2(av[z8], bv[z8]);
  }
}

// ---------------- Kernel 1: FUSED qkv + windowed attention (v2) -----------
// One (window, head, half) per 512-thread block, grid 1728. X fragments read
// DIRECTLY from xw (per-lane contiguous 16 B, L2-hot: 8 blocks/window share
// 64 KB) -> no xs LDS. LDS = kfl/vfl only (64 KB) -> 2 blocks/CU;
// __launch_bounds__(512,4) pins unified regs <=128 so both blocks fit
// (R19: 88 VGPR + AGPRs > 128 -> 1 block -> 21% occupancy -> 165us).
//   Q: D = W_q.X    -> pack_fr -> B-frag (qf)
//   K: D = W_k.X    -> pack_fr -> A-frag (kf, LDS)
//   V: D = X^T.W_v^T-> pack_fr -> B-frag (vf, LDS)
// No-max softmax; row-sums on MFMA pipe. att: [216 w][512 n][128 hc].

__device__ __forceinline__ void attn_step(bf16x8 kf0, bf16x8 kf1, bf16x8 vf0, bf16x8 vf1,
                                          bf16x8 q0, bf16x8 q1, const f32x16& z, bf16x8 ones,
                                          f32x16& O, f32x16& Sm) {
  f32x16 S = mfma32(kf0, q0, z);
  S = mfma32(kf1, q1, S);
  #pragma unroll
  for (int r = 0; r < 16; ++r) S[r] = fexp2(S[r]);
  bf16x8 pf0, pf1;
  pack_fr(S, pf0, pf1);
  O = mfma32(pf0, vf0, O);
  O = mfma32(pf1, vf1, O);
  Sm = mfma32(pf0, ones, Sm);
  Sm = mfma32(pf1, ones, Sm);
}

__global__ __launch_bounds__(512, 4) void fattn_kernel(const bf16_t* __restrict__ xw,
                                                       const float* __restrict__ w_qkv,
                                                       bf16_t* __restrict__ att) {
  __shared__ u32x4 kfl[16][2][64];     // K frags [tile][chunk][lane] 32 KB
  __shared__ u32x4 vfl[16][2][64];     // V frags                     32 KB
  const int blk = blockIdx.x;
  const int wh = blk >> 1, half = blk & 1;
  const int w = wh >> 2, h = wh & 3;
  const int t = threadIdx.x, lane = t & 63, wv = t >> 6;
  const int l31 = lane & 31, hi = lane >> 5;
  const float SC = 0.25505003946337226f;  // log2(e)/sqrt(32)
  const bf16_t* xb_base = xw + (size_t)w * 512 * 64;

  // W fragments (per lane, direct from global; L2-hot 96 KB):
  bf16x8 wqf[4], wkf[4], wvf[4];
  #pragma unroll
  for (int cch = 0; cch < 4; ++cch) {
    const float* q_r = w_qkv + (h * 32 + l31) * 64 + cch * 16 + 8 * hi;
    const float* k_r = q_r + 128 * 64;
    const float* v_r = q_r + 256 * 64;
    float4 u0, u1;
    bf16x8 f;
    u0 = reinterpret_cast<const float4*>(q_r)[0]; u1 = reinterpret_cast<const float4*>(q_r)[1];
    f[0]=(bf16_t)(u0.x*SC); f[1]=(bf16_t)(u0.y*SC); f[2]=(bf16_t)(u0.z*SC); f[3]=(bf16_t)(u0.w*SC);
    f[4]=(bf16_t)(u1.x*SC); f[5]=(bf16_t)(u1.y*SC); f[6]=(bf16_t)(u1.z*SC); f[7]=(bf16_t)(u1.w*SC);
    wqf[cch] = f;
    u0 = reinterpret_cast<const float4*>(k_r)[0]; u1 = reinterpret_cast<const float4*>(k_r)[1];
    f[0]=(bf16_t)u0.x; f[1]=(bf16_t)u0.y; f[2]=(bf16_t)u0.z; f[3]=(bf16_t)u0.w;
    f[4]=(bf16_t)u1.x; f[5]=(bf16_t)u1.y; f[6]=(bf16_t)u1.z; f[7]=(bf16_t)u1.w;
    wkf[cch] = f;
    u0 = reinterpret_cast<const float4*>(v_r)[0]; u1 = reinterpret_cast<const float4*>(v_r)[1];
    f[0]=(bf16_t)u0.x; f[1]=(bf16_t)u0.y; f[2]=(bf16_t)u0.z; f[3]=(bf16_t)u0.w;
    f[4]=(bf16_t)u1.x; f[5]=(bf16_t)u1.y; f[6]=(bf16_t)u1.z; f[7]=(bf16_t)u1.w;
    wvf[cch] = f;
  }

  const f32x16 z = {};
  const int qbase = half * 256 + wv * 32;   // this wave's 32 q-rows

  // Q phase: D = W_q.X; B-operand = xw row (qbase+l31), c = cch*16+8hi+e
  f32x16 Dq = z;
  #pragma unroll
  for (int cch = 0; cch < 4; ++cch) {
    bf16x8 xb = *(const bf16x8*)(xb_base + (qbase + l31) * 64 + cch * 16 + 8 * hi);
    Dq = mfma32(wqf[cch], xb, Dq);
  }
  bf16x8 qf0, qf1;
  pack_fr(Dq, qf0, qf1);

  // K,V phase: wave computes tiles 2wv, 2wv+1 (32 k-rows each)
  #pragma unroll
  for (int i = 0; i < 2; ++i) {
    int kt = 2 * wv + i;
    bf16x8 xf[4];
    #pragma unroll
    for (int cch = 0; cch < 4; ++cch)
      xf[cch] = *(const bf16x8*)(xb_base + (kt * 32 + l31) * 64 + cch * 16 + 8 * hi);
    f32x16 Dk = z, Dv = z;
    #pragma unroll
    for (int cch = 0; cch < 4; ++cch) {
      Dk = mfma32(wkf[cch], xf[cch], Dk);   // D[d][k-col]
      Dv = mfma32(xf[cch], wvf[cch], Dv);   // D[k-row][d-col]
    }
    bf16x8 a, b;
    pack_fr(Dk, a, b);
    kfl[kt][0][lane] = __builtin_bit_cast(u32x4, a);
    kfl[kt][1][lane] = __builtin_bit_cast(u32x4, b);
    pack_fr(Dv, a, b);
    vfl[kt][0][lane] = __builtin_bit_cast(u32x4, a);
    vfl[kt][1][lane] = __builtin_bit_cast(u32x4, b);
  }
  __syncthreads();

  f32x16 O = {}, Sm = {};
  bf16x8 ones;
  #pragma unroll
  for (int e = 0; e < 8; ++e) ones[e] = (bf16_t)1.0f;

  for (int kt = 0; kt < 16; ++kt) {
    bf16x8 kf0 = __builtin_bit_cast(bf16x8, kfl[kt][0][lane]);
    bf16x8 kf1 = __builtin_bit_cast(bf16x8, kfl[kt][1][lane]);
    bf16x8 vf0 = __builtin_bit_cast(bf16x8, vfl[kt][0][lane]);
    bf16x8 vf1 = __builtin_bit_cast(bf16x8, vfl[kt][1][lane]);
    attn_step(kf0, kf1, vf0, vf1, qf0, qf1, z, ones, O, Sm);
  }

  // normalize + store: O/Sm reg r -> row q = (r&3)+8*(r>>2)+4*hi, col d = l31
  #pragma unroll
  for (int r = 0; r < 16; ++r) {
    int qr = (r & 3) + 8 * (r >> 2) + 4 * hi;
    int n = qbase + qr;
    float ri = __builtin_amdgcn_rcpf(Sm[r]);
    att[((size_t)w * 512 + n) * 128 + h * 32 + l31] = (bf16_t)(O[r] * ri);
  }
}

// ---------------- Kernel 2: merge-heads 1x1x1 conv via MFMA ----------------
// Grid 864 = 216 windows x 4 quarters, 256 threads; w_out staged once per
// block into LDS bf16 (R16 proven config).
__global__ __launch_bounds__(256) void proj_kernel(const bf16_t* __restrict__ att,
                                                   const float* __restrict__ w_out,
                                                   const float* __restrict__ b_out,
                                                   float* __restrict__ out) {
  __shared__ bf16_t ws[64][136];   // [o][c] pad 136 -> 17.4 KB
  const int blk = blockIdx.x;
  const int w = blk >> 2, quarter = blk & 3;
  const int wx = w / 36, wy = (w / 6) % 6, wz = w % 6;
  const int t = threadIdx.x, lane = t & 63, wv = t >> 6;
  const int q16 = lane & 15, g = lane >> 4;

  {
    int o = t >> 2, c0 = (t & 3) * 32;
    const float* wr = w_out + o * 128 + c0;
    #pragma unroll
    for (int u = 0; u < 4; ++u) {
      float4 a = reinterpret_cast<const float4*>(wr)[2 * u];
      float4 b = reinterpret_cast<const float4*>(wr)[2 * u + 1];
      *(unsigned int*)&ws[o][c0 + 8 * u]     = pk2(a.x, a.y);
      *(unsigned int*)&ws[o][c0 + 8 * u + 2] = pk2(a.z, a.w);
      *(unsigned int*)&ws[o][c0 + 8 * u + 4] = pk2(b.x, b.y);
      *(unsigned int*)&ws[o][c0 + 8 * u + 6] = pk2(b.z, b.w);
    }
  }
  float4 bias[4];
  #pragma unroll
  for (int ot = 0; ot < 4; ++ot)
    bias[ot] = *reinterpret_cast<const float4*>(b_out + ot * 16 + 4 * g);
  __syncthreads();

  bf16x8 aw[4][4];
  #pragma unroll
  for (int ot = 0; ot < 4; ++ot)
    #pragma unroll
    for (int kc = 0; kc < 4; ++kc)
      aw[ot][kc] = *(const bf16x8*)&ws[ot * 16 + q16][kc * 32 + 8 * g];

  #pragma unroll
  for (int i = 0; i < 2; ++i) {
    int n = quarter * 128 + (wv * 2 + i) * 16 + q16;
    const bf16_t* ar = att + ((size_t)w * 512 + n) * 128;
    bf16x8 bf[4];
    #pragma unroll
    for (int kc = 0; kc < 4; ++kc)
      bf[kc] = *(const bf16x8*)(ar + kc * 32 + 8 * g);
    int ix = n >> 6, iy = (n >> 3) & 7, iz = n & 7;
    int v = ((wx * 8 + ix) * 48 + wy * 8 + iy) * 48 + wz * 8 + iz;
    #pragma unroll
    for (int ot = 0; ot < 4; ++ot) {
      f32x4 acc = {0.f, 0.f, 0.f, 0.f};
      #pragma unroll
      for (int kc = 0; kc < 4; ++kc)
        acc = mfma16(aw[ot][kc], bf[kc], acc);
      #pragma unroll
      for (int r = 0; r < 4; ++r) {
        int o = ot * 16 + 4 * g + r;
        out[(size_t)o * NVOX + v] = acc[r] + ((const float*)&bias[ot])[r];
      }
    }
  }
}

extern "C" void kernel_launch(void* const* d_in, const int* in_sizes, int n_in,
                              void* d_out, int out_size, void* d_ws, size_t ws_size,
                              hipStream_t stream) {
  const float* x     = (const float*)d_in[0];
  const float* w_qkv = (const float*)d_in[1];
  const float* w_out = (const float*)d_in[2];
  const float* b_out = (const float*)d_in[3];
  float* out = (float*)d_out;
  // ws: xw bf16 [216][512][64] = 14,155,776 B; att bf16 [216][512][128] = 28,311,552 B
  bf16_t* xw  = (bf16_t*)d_ws;
  bf16_t* att = (bf16_t*)((char*)d_ws + (size_t)NWIN * 512 * 64 * 2);
  xprep_kernel<<<dim3(NWIN), dim3(512), 0, stream>>>(x, xw);
  fattn_kernel<<<dim3(NWIN * 4 * 2), dim3(512), 0, stream>>>(xw, w_qkv, att);
  proj_kernel<<<dim3(NWIN * 4), dim3(256), 0, stream>>>(att, w_out, b_out, out);
}

// Round 21
// 108.411 us; speedup vs baseline: 1.5272x; 1.0977x over previous
//
#include <hip/hip_runtime.h>
#include <hip/hip_bf16.h>
#include <stdint.h>

#define NWIN 216      // 6^3 windows
#define NVOX 110592   // 48^3

typedef __bf16 bf16_t;
typedef __attribute__((ext_vector_type(8))) __bf16 bf16x8;
typedef __attribute__((ext_vector_type(4))) __bf16 bf16x4;
typedef __attribute__((ext_vector_type(4))) float f32x4;
typedef __attribute__((ext_vector_type(16))) float f32x16;
typedef __attribute__((ext_vector_type(4))) unsigned int u32x4;
typedef __attribute__((ext_vector_type(2))) unsigned int u32x2;

__device__ __forceinline__ f32x4 mfma16(bf16x8 a, bf16x8 b, f32x4 c) {
  return __builtin_amdgcn_mfma_f32_16x16x32_bf16(a, b, c, 0, 0, 0);
}
__device__ __forceinline__ f32x16 mfma32(bf16x8 a, bf16x8 b, f32x16 c) {
  return __builtin_amdgcn_mfma_f32_32x32x16_bf16(a, b, c, 0, 0, 0);
}

// single v_exp_f32 (libcall exp2f was ~12 instrs -> was 63% VALUBusy)
__device__ __forceinline__ float fexp2(float x) {
  return __builtin_amdgcn_exp2f(x);
}

__device__ __forceinline__ unsigned int pk2(float lo, float hi) {
  unsigned short l = __builtin_bit_cast(unsigned short, (bf16_t)lo);
  unsigned short h = __builtin_bit_cast(unsigned short, (bf16_t)hi);
  return (unsigned int)l | ((unsigned int)h << 16);
}

// Exchange a.hi(lanes32-63) <-> b.lo(lanes0-31).
__device__ __forceinline__ void swap_half(unsigned int& a, unsigned int& b) {
#if __has_builtin(__builtin_amdgcn_permlane32_swap)
  u32x2 r = __builtin_amdgcn_permlane32_swap(a, b, false, false);
  a = r[0]; b = r[1];
#else
  asm("v_permlane32_swap_b32 %0, %1" : "+v"(a), "+v"(b));
#endif
}

// ---------------- Kernel 1: QKV 1x1x1 conv + window gather ----------------
// One 512-thread block per window (R16 best config; R15/R17 splits were
// flat-to-negative). x read once; W A-frags direct from global (L2-hot).
// qkv layout: [3][216][4][512][32] bf16; q pre-scaled by log2(e)/sqrt(32).
__global__ __launch_bounds__(512, 2) void qkv_kernel(const float* __restrict__ x,
                                                     const float* __restrict__ w_qkv,
                                                     bf16_t* __restrict__ qkv) {
  __shared__ bf16_t xs[512][72];   // [n][c] pad: 144-B rows, 16-B aligned  73.7 KB
  const int w = blockIdx.x;
  const int wx = w / 36, wy = (w / 6) % 6, wz = w % 6;
  const int t = threadIdx.x;
  const int lane = t & 63;
  const int q16 = lane & 15, g = lane >> 4;
  const float SC = 0.25505003946337226f;  // log2(e)/sqrt(32)

  // stage x window -> xs[n][c]: c-pair packed b32 writes
  #pragma unroll
  for (int i = 0; i < 4; ++i) {
    int seg = t + 512 * i;               // 2048 segs: cpair(32) x xy(64)
    int cpair = seg & 31, xy = seg >> 5;
    int ix = xy >> 3, iy = xy & 7;
    const float* s0 = x + (((2 * cpair) * 48 + wx * 8 + ix) * 48 + wy * 8 + iy) * 48 + wz * 8;
    const float* s1 = s0 + 48 * 48 * 48;
    float4 a0 = reinterpret_cast<const float4*>(s0)[0];
    float4 a1 = reinterpret_cast<const float4*>(s0)[1];
    float4 b0 = reinterpret_cast<const float4*>(s1)[0];
    float4 b1 = reinterpret_cast<const float4*>(s1)[1];
    float av[8] = {a0.x, a0.y, a0.z, a0.w, a1.x, a1.y, a1.z, a1.w};
    float bv[8] = {b0.x, b0.y, b0.z, b0.w, b1.x, b1.y, b1.z, b1.w};
    #pragma unroll
    for (int z = 0; z < 8; ++z)
      *(unsigned int*)&xs[xy * 8 + z][2 * cpair] = pk2(av[z], bv[z]);
  }

  const int wv = t >> 6;                 // 8 waves; wave owns o-tiles wv*3 .. wv*3+2
  // A = W[o][c]: lane row o = wv*48+j*16+q16, c = s*32+8g+e (direct global).
  bf16x8 aw[3][2];
  #pragma unroll
  for (int j = 0; j < 3; ++j) {
    int o = wv * 48 + j * 16 + q16;
    float sc = (o < 128) ? SC : 1.0f;    // frag spans 16 o-rows, never crosses 128
    #pragma unroll
    for (int s = 0; s < 2; ++s) {
      const float* wr = w_qkv + o * 64 + s * 32 + 8 * g;
      float4 u0 = reinterpret_cast<const float4*>(wr)[0];
      float4 u1 = reinterpret_cast<const float4*>(wr)[1];
      bf16x8 f;
      f[0]=(bf16_t)(u0.x*sc); f[1]=(bf16_t)(u0.y*sc); f[2]=(bf16_t)(u0.z*sc); f[3]=(bf16_t)(u0.w*sc);
      f[4]=(bf16_t)(u1.x*sc); f[5]=(bf16_t)(u1.y*sc); f[6]=(bf16_t)(u1.z*sc); f[7]=(bf16_t)(u1.w*sc);
      aw[j][s] = f;
    }
  }
  __syncthreads();

  for (int nt = 0; nt < 32; ++nt) {
    int n = nt * 16 + q16;
    bf16x8 xb0 = *(const bf16x8*)&xs[n][8 * g];       // B[c][n]: lane col n, c=8g+e
    bf16x8 xb1 = *(const bf16x8*)&xs[n][32 + 8 * g];
    #pragma unroll
    for (int j = 0; j < 3; ++j) {
      f32x4 acc = {0.f, 0.f, 0.f, 0.f};
      acc = mfma16(aw[j][0], xb0, acc);
      acc = mfma16(aw[j][1], xb1, acc);
      // D: row = o-local = 4g+r, col = n-local = lane&15
      int ob = wv * 48 + j * 16 + 4 * g;   // multiple of 4
      int sel = ob >> 7, rem = ob & 127, hh = rem >> 5, dd = rem & 31;
      bf16x4 pk;
      pk[0] = (bf16_t)acc[0]; pk[1] = (bf16_t)acc[1];
      pk[2] = (bf16_t)acc[2]; pk[3] = (bf16_t)acc[3];
      *(bf16x4*)(qkv + ((((size_t)sel * NWIN + w) * 4 + hh) * 512 + n) * 32 + dd) = pk;
    }
  }
}

// ---------------- Kernel 2: windowed attention, 32x32 MFMA + permlane32_swap ----
// QB1 (one 32-row q-tile per wave); block = (window, head, half), 512 threads.
// VALU+trans issue-bound plateau at 57.7us (R14-R18: occupancy, reg-class,
// S-pipelining, sum-placement all flat -> 87% combined pipe utilization is
// this structure's limit). Row-sums on the MFMA pipe (P x ones); K frags from
// global pipelined one kt ahead; V^T in LDS. No-max softmax (|s| small,
// exp2 exact). att layout: [216 w][512 n][128 hc].

__device__ __forceinline__ void attn_step(bf16x8 kf0, bf16x8 kf1, bf16x8 vf0, bf16x8 vf1,
                                          bf16x8 q0, bf16x8 q1, const f32x16& z, bf16x8 ones,
                                          f32x16& O, f32x16& Sm) {
  // S^T tile: col q = l31, row k = (r&3) + 8*(r>>2) + 4*hi
  f32x16 S = mfma32(kf0, q0, z);
  S = mfma32(kf1, q1, S);
  #pragma unroll
  for (int r = 0; r < 16; ++r) S[r] = fexp2(S[r]);
  // pack P pairs; half-wave exchange -> PV A-frag (k = kchunk*16 + 8hi + e)
  unsigned int p01 = pk2(S[0], S[1]),   p23 = pk2(S[2], S[3]);
  unsigned int p45 = pk2(S[4], S[5]),   p67 = pk2(S[6], S[7]);
  unsigned int p89 = pk2(S[8], S[9]),   pab = pk2(S[10], S[11]);
  unsigned int pcd = pk2(S[12], S[13]), pef = pk2(S[14], S[15]);
  swap_half(p01, p45);
  swap_half(p23, p67);
  swap_half(p89, pcd);
  swap_half(pab, pef);
  u32x4 u0 = {p01, p23, p45, p67};
  u32x4 u1 = {p89, pab, pcd, pef};
  bf16x8 pf0 = __builtin_bit_cast(bf16x8, u0);
  bf16x8 pf1 = __builtin_bit_cast(bf16x8, u1);
  O = mfma32(pf0, vf0, O);
  O = mfma32(pf1, vf1, O);
  Sm = mfma32(pf0, ones, Sm);   // row-sum tile: D[q][*] = sum_k P[q][k]
  Sm = mfma32(pf1, ones, Sm);
}

__global__ __launch_bounds__(512, 2) void attn_kernel(const bf16_t* __restrict__ qkv,
                                                      bf16_t* __restrict__ att) {
  __shared__ bf16_t vt[32][520];    // V^T [d][n], padded rows -> 33.3 KB
  const int blk = blockIdx.x;
  const int wh = blk >> 1, half = blk & 1;
  const int w = wh >> 2, h = wh & 3;
  const bf16_t* qb = qkv + ((size_t)(0 * NWIN + w) * 4 + h) * 16384;
  const bf16_t* kb = qkv + ((size_t)(1 * NWIN + w) * 4 + h) * 16384;
  const bf16_t* vb = qkv + ((size_t)(2 * NWIN + w) * 4 + h) * 16384;
  const int t = threadIdx.x, lane = t & 63, wv = t >> 6;
  const int l31 = lane & 31, hi = lane >> 5;
  const int qbase = half * 256 + wv * 32;   // this wave's 32 q-rows

  // Q fragments (B-frag: col q = l31, row c = cch*16 + 8*hi + e)
  bf16x8 qf0 = *(const bf16x8*)(qb + (qbase + l31) * 32 + 8 * hi);
  bf16x8 qf1 = *(const bf16x8*)(qb + (qbase + l31) * 32 + 16 + 8 * hi);

  // stage V^T: paired-row transpose, packed b32 LDS writes (no scalar b16).
  #pragma unroll
  for (int i = 0; i < 2; ++i) {
    int task = i * 512 + t;            // 1024 tasks: p(256) x dg(4)
    int p = task >> 2, dg = task & 3;
    bf16x8 v0 = *(const bf16x8*)(vb + (2 * p) * 32 + 8 * dg);
    bf16x8 v1 = *(const bf16x8*)(vb + (2 * p + 1) * 32 + 8 * dg);
    u32x4 a = __builtin_bit_cast(u32x4, v0);
    u32x4 b = __builtin_bit_cast(u32x4, v1);
    #pragma unroll
    for (int j = 0; j < 4; ++j) {
      unsigned int lo = (a[j] & 0xffffu) | (b[j] << 16);              // elem 2j
      unsigned int hh = (a[j] >> 16) | (b[j] & 0xffff0000u);          // elem 2j+1
      *(unsigned int*)&vt[dg * 8 + 2 * j][2 * p]     = lo;
      *(unsigned int*)&vt[dg * 8 + 2 * j + 1][2 * p] = hh;
    }
  }
  __syncthreads();

  f32x16 O = {}, Sm = {};
  const f32x16 z = {};
  bf16x8 ones;
  #pragma unroll
  for (int e = 0; e < 8; ++e) ones[e] = (bf16_t)1.0f;

  const bf16_t* kptr = kb + l31 * 32 + 8 * hi;   // + kt*1024
  bf16x8 kf0 = *(const bf16x8*)(kptr);
  bf16x8 kf1 = *(const bf16x8*)(kptr + 16);
  for (int kt = 0; kt < 15; ++kt) {
    // prefetch next K tile (global) before computing current
    const bf16_t* nk = kptr + (kt + 1) * 1024;
    bf16x8 nkf0 = *(const bf16x8*)(nk);
    bf16x8 nkf1 = *(const bf16x8*)(nk + 16);
    bf16x8 vf0 = *(const bf16x8*)&vt[l31][kt * 32 + 8 * hi];
    bf16x8 vf1 = *(const bf16x8*)&vt[l31][kt * 32 + 8 * hi + 16];
    attn_step(kf0, kf1, vf0, vf1, qf0, qf1, z, ones, O, Sm);
    kf0 = nkf0; kf1 = nkf1;
  }
  {
    bf16x8 vf0 = *(const bf16x8*)&vt[l31][15 * 32 + 8 * hi];
    bf16x8 vf1 = *(const bf16x8*)&vt[l31][15 * 32 + 8 * hi + 16];
    attn_step(kf0, kf1, vf0, vf1, qf0, qf1, z, ones, O, Sm);
  }

  // normalize + store: O/Sm reg r -> row q = (r&3)+8*(r>>2)+4*hi, col d = l31.
  // Sm[r] = row-sum (replicated over cols) -> per-lane rcp, no shuffles.
  #pragma unroll
  for (int r = 0; r < 16; ++r) {
    int qr = (r & 3) + 8 * (r >> 2) + 4 * hi;
    int n = qbase + qr;
    float ri = __builtin_amdgcn_rcpf(Sm[r]);
    att[((size_t)w * 512 + n) * 128 + h * 32 + l31] = (bf16_t)(O[r] * ri);
  }
}

// ---------------- Kernel 3: merge-heads 1x1x1 conv via MFMA ----------------
// Grid 864 = 216 windows x 4 quarters, 256 threads. w_out staged ONCE per
// block into LDS bf16 (R15 lesson: the 32x global-float4 per-thread prologue
// made grid-splitting net-negative; LDS staging cuts it ~10x, making the
// 3.4-waves/SIMD TLP affordable). ws +8 pad -> ~2-way bank conflict on b128.
__global__ __launch_bounds__(256) void proj_kernel(const bf16_t* __restrict__ att,
                                                   const float* __restrict__ w_out,
                                                   const float* __restrict__ b_out,
                                                   float* __restrict__ out) {
  __shared__ bf16_t ws[64][136];   // [o][c] pad 136 -> 17.4 KB
  const int blk = blockIdx.x;
  const int w = blk >> 2, quarter = blk & 3;
  const int wx = w / 36, wy = (w / 6) % 6, wz = w % 6;
  const int t = threadIdx.x, lane = t & 63, wv = t >> 6;
  const int q16 = lane & 15, g = lane >> 4;

  // stage w_out -> LDS bf16: thread t covers row t>>2, col-block (t&3)*32
  {
    int o = t >> 2, c0 = (t & 3) * 32;
    const float* wr = w_out + o * 128 + c0;
    #pragma unroll
    for (int u = 0; u < 4; ++u) {
      float4 a = reinterpret_cast<const float4*>(wr)[2 * u];
      float4 b = reinterpret_cast<const float4*>(wr)[2 * u + 1];
      *(unsigned int*)&ws[o][c0 + 8 * u]     = pk2(a.x, a.y);
      *(unsigned int*)&ws[o][c0 + 8 * u + 2] = pk2(a.z, a.w);
      *(unsigned int*)&ws[o][c0 + 8 * u + 4] = pk2(b.x, b.y);
      *(unsigned int*)&ws[o][c0 + 8 * u + 6] = pk2(b.z, b.w);
    }
  }
  float4 bias[4];
  #pragma unroll
  for (int ot = 0; ot < 4; ++ot)
    bias[ot] = *reinterpret_cast<const float4*>(b_out + ot * 16 + 4 * g);
  __syncthreads();

  // A-frags from LDS: aw[ot][kc]: o = ot*16 + q16, c = kc*32 + 8g + e
  bf16x8 aw[4][4];
  #pragma unroll
  for (int ot = 0; ot < 4; ++ot)
    #pragma unroll
    for (int kc = 0; kc < 4; ++kc)
      aw[ot][kc] = *(const bf16x8*)&ws[ot * 16 + q16][kc * 32 + 8 * g];

  #pragma unroll
  for (int i = 0; i < 2; ++i) {
    int n = quarter * 128 + (wv * 2 + i) * 16 + q16;
    const bf16_t* ar = att + ((size_t)w * 512 + n) * 128;
    bf16x8 bf[4];
    #pragma unroll
    for (int kc = 0; kc < 4; ++kc)
      bf[kc] = *(const bf16x8*)(ar + kc * 32 + 8 * g);
    int ix = n >> 6, iy = (n >> 3) & 7, iz = n & 7;
    int v = ((wx * 8 + ix) * 48 + wy * 8 + iy) * 48 + wz * 8 + iz;
    #pragma unroll
    for (int ot = 0; ot < 4; ++ot) {
      f32x4 acc = {0.f, 0.f, 0.f, 0.f};
      #pragma unroll
      for (int kc = 0; kc < 4; ++kc)
        acc = mfma16(aw[ot][kc], bf[kc], acc);
      #pragma unroll
      for (int r = 0; r < 4; ++r) {
        int o = ot * 16 + 4 * g + r;
        out[(size_t)o * NVOX + v] = acc[r] + ((const float*)&bias[ot])[r];
      }
    }
  }
}

extern "C" void kernel_launch(void* const* d_in, const int* in_sizes, int n_in,
                              void* d_out, int out_size, void* d_ws, size_t ws_size,
                              hipStream_t stream) {
  const float* x     = (const float*)d_in[0];
  const float* w_qkv = (const float*)d_in[1];
  const float* w_out = (const float*)d_in[2];
  const float* b_out = (const float*)d_in[3];
  float* out = (float*)d_out;
  // ws: qkv bf16 [3][216][4][512][32] = 84,934,656 B; att bf16 [216][512][128] = 28,311,552 B
  bf16_t* qkv = (bf16_t*)d_ws;
  bf16_t* att = (bf16_t*)((char*)d_ws + (size_t)3 * NWIN * 4 * 512 * 32 * 2);
  qkv_kernel<<<dim3(NWIN), dim3(512), 0, stream>>>(x, w_qkv, qkv);
  attn_kernel<<<dim3(NWIN * 4 * 2), dim3(512), 0, stream>>>(qkv, att);
  proj_kernel<<<dim3(NWIN * 4), dim3(256), 0, stream>>>(att, w_out, b_out, out);
}